// Round 4
// baseline (325.373 us; speedup 1.0000x reference)
//
#include <hip/hip_runtime.h>
#include <stdint.h>

typedef __bf16 bf16_t;
typedef __bf16 bf16x4 __attribute__((ext_vector_type(4)));
typedef __bf16 bf16x8 __attribute__((ext_vector_type(8)));
typedef float  f32x4  __attribute__((ext_vector_type(4)));
typedef float  f32x16 __attribute__((ext_vector_type(16)));

#define BB   4
#define SS   2048
#define DD   1024
#define HH   16
#define DH   64

#if __has_builtin(__builtin_amdgcn_exp2f)
#define EXP2F(x) __builtin_amdgcn_exp2f(x)
#else
#define EXP2F(x) __expf((x) * 0.6931471805599453f)
#endif

// ---------------------------------------------------------------- helpers
__device__ __forceinline__ void gload_lds16(const void* g, void* l) {
    // dest LDS addr = wave-uniform base + lane*16 (measured m104/m108)
    __builtin_amdgcn_global_load_lds(
        (__attribute__((address_space(1))) void*)(uintptr_t)g,
        (__attribute__((address_space(3))) void*)(uint32_t)(uintptr_t)l,
        16, 0, 0);
}

// ---------------------------------------------------------------- fp32 -> bf16 converts
__global__ __launch_bounds__(256) void cvt_kernel(const float* __restrict__ src,
                                                  bf16_t* __restrict__ dst, int n4) {
    int i = blockIdx.x * 256 + threadIdx.x;
    if (i < n4) {
        float4 v = ((const float4*)src)[i];
        bf16x4 o;
        o.x = (bf16_t)v.x; o.y = (bf16_t)v.y; o.z = (bf16_t)v.z; o.w = (bf16_t)v.w;
        ((bf16x4*)dst)[i] = o;
    }
}

// all four weight matrices in one launch (each 1024x1024 fp32 = 262144 float4)
__global__ __launch_bounds__(256) void cvt_weights(const float* __restrict__ Wq,
                                                   const float* __restrict__ Wk,
                                                   const float* __restrict__ Wv,
                                                   const float* __restrict__ Wo,
                                                   bf16_t* __restrict__ Wqkv,
                                                   bf16_t* __restrict__ Wob) {
    int i = blockIdx.x * 256 + threadIdx.x;      // 0 .. 4*262144
    int which = i >> 18, p = i & 262143;
    const float* src = (which == 0) ? Wq : (which == 1) ? Wk : (which == 2) ? Wv : Wo;
    bf16_t* dst = (which < 3) ? (Wqkv + (long)which * 1048576) : Wob;
    float4 v = ((const float4*)src)[p];
    bf16x4 o;
    o.x = (bf16_t)v.x; o.y = (bf16_t)v.y; o.z = (bf16_t)v.z; o.w = (bf16_t)v.w;
    ((bf16x4*)dst)[p] = o;
}

__global__ __launch_bounds__(256) void pack_bias(const float* __restrict__ bq,
                                                 const float* __restrict__ bk,
                                                 const float* __restrict__ bv,
                                                 float* __restrict__ bqkv) {
    int i = blockIdx.x * 256 + threadIdx.x;
    if (i < 3072)
        bqkv[i] = (i < 1024) ? bq[i] : ((i < 2048) ? bk[i - 1024] : bv[i - 2048]);
}

// cos/sin table: tab[s*512 + pr] = {cos(s*invf), sin(s*invf)}, invf = 10000^(-2pr/1024)
__global__ __launch_bounds__(256) void rope_tab(float2* __restrict__ tab) {
    int i = blockIdx.x * 256 + threadIdx.x;      // 2048*512
    int s = i >> 9, pr = i & 511;
    float inv = powf(10000.0f, -(float)(2 * pr) * (1.0f / 1024.0f));
    float c, sn;
    sincosf((float)s * inv, &sn, &c);
    tab[i] = make_float2(c, sn);
}

// ---------------------------------------------------------------- fused QKV GEMM + bias + RoPE
__global__ __launch_bounds__(256, 2) void gemm_qkv_rope(
        const bf16_t* __restrict__ A, const bf16_t* __restrict__ Bm,
        const float* __restrict__ bias, const float2* __restrict__ tab,
        bf16_t* __restrict__ Qb, bf16_t* __restrict__ Kb, bf16_t* __restrict__ Vtmp)
{
    __shared__ __attribute__((aligned(16))) bf16_t As[128 * 32];
    __shared__ __attribute__((aligned(16))) bf16_t Bs[128 * 32];
    const int t = threadIdx.x;
    const int lane = t & 63, w = t >> 6;
    const int wm = w >> 1, wn = w & 1;
    const int l15 = lane & 15, l4 = lane >> 4;
    const long rowA0 = (long)blockIdx.x * 128;
    const long rowB0 = (long)blockIdx.y * 128;
    const int K = 1024, N = 1024;  // per-part N

    const f32x4 vz = {0.f, 0.f, 0.f, 0.f};
    f32x4 acc[4][4];
#pragma unroll
    for (int i = 0; i < 4; ++i)
#pragma unroll
        for (int j = 0; j < 4; ++j) acc[i][j] = vz;

    for (int kk = 0; kk < K; kk += 32) {
        __syncthreads();
#pragma unroll
        for (int i = 0; i < 2; ++i) {
            const int cb = i * 256 + w * 64;
            const int c  = cb + lane;
            const int r  = c >> 2;
            const int ko = (c & 3) << 3;
            gload_lds16(A  + (rowA0 + r) * K + kk + ko, As + cb * 8);
            gload_lds16(Bm + (rowB0 + r) * K + kk + ko, Bs + cb * 8);
        }
        __syncthreads();
        bf16x8 af[4], bfr[4];
#pragma unroll
        for (int i = 0; i < 4; ++i)
            af[i] = *(const bf16x8*)(As + (wm * 64 + i * 16 + l15) * 32 + l4 * 8);
#pragma unroll
        for (int j = 0; j < 4; ++j)
            bfr[j] = *(const bf16x8*)(Bs + (wn * 64 + j * 16 + l15) * 32 + l4 * 8);
#pragma unroll
        for (int i = 0; i < 4; ++i)
#pragma unroll
            for (int j = 0; j < 4; ++j)
                acc[i][j] = __builtin_amdgcn_mfma_f32_16x16x32_bf16(af[i], bfr[j], acc[i][j], 0, 0, 0);
    }

    const long crow0 = rowA0 + wm * 64;
    const int  ccol0 = (int)rowB0 + wn * 64;     // global col in [0,3072), multiple of 64
    const int  part  = blockIdx.y >> 3;          // 0=Q, 1=K, 2=V

    if (part == 2) {
#pragma unroll
        for (int i = 0; i < 4; ++i) {
#pragma unroll
            for (int j = 0; j < 4; ++j) {
                const int col = ccol0 + j * 16 + l15;
                const float bb = bias[col];
                const int vc = col - 2048;
#pragma unroll
                for (int r = 0; r < 4; ++r) {
                    const long row = crow0 + i * 16 + l4 * 4 + r;
                    Vtmp[row * N + vc] = (bf16_t)(acc[i][j][r] + bb);
                }
            }
        }
    } else {
        bf16_t* dst0 = part ? Kb : Qb;
        const int h = (ccol0 & 1023) >> 6;       // this wave's 64-col strip = one head
#pragma unroll
        for (int i = 0; i < 4; ++i) {
#pragma unroll
            for (int j = 0; j < 4; ++j) {
                const int col = ccol0 + j * 16 + l15;
                const float bb = bias[col];
                const int even = !(col & 1);
                const int dd = j * 16 + l15;
                const float2* trow = tab + (col >> 1 & 511);
#pragma unroll
                for (int r = 0; r < 4; ++r) {
                    const long row = crow0 + i * 16 + l4 * 4 + r;
                    const int b = (int)(row >> 11), s = (int)(row & 2047);
                    const float val = acc[i][j][r] + bb;
                    const float par = __shfl_xor(val, 1);
                    const float2 cs = trow[s * 512];
                    const float out = even ? (val * cs.x - par * cs.y)
                                           : fmaf(val, cs.x, par * cs.y);
                    dst0[((long)((b * HH + h) * SS + s)) * DH + dd] = (bf16_t)out;
                }
            }
        }
    }
}

// ---------------------------------------------------------------- NT GEMM (output projection)
template <int OUT_BF16>
__global__ __launch_bounds__(256, 2) void gemm_bt(
        const bf16_t* __restrict__ A, const bf16_t* __restrict__ Bm,
        const float* __restrict__ bias, void* __restrict__ Cout,
        int M, int N, int K)
{
    __shared__ __attribute__((aligned(16))) bf16_t As[128 * 32];
    __shared__ __attribute__((aligned(16))) bf16_t Bs[128 * 32];
    const int t = threadIdx.x;
    const int lane = t & 63, w = t >> 6;
    const int wm = w >> 1, wn = w & 1;
    const int l15 = lane & 15, l4 = lane >> 4;
    const long rowA0 = (long)blockIdx.x * 128;
    const long rowB0 = (long)blockIdx.y * 128;

    const f32x4 vz = {0.f, 0.f, 0.f, 0.f};
    f32x4 acc[4][4];
#pragma unroll
    for (int i = 0; i < 4; ++i)
#pragma unroll
        for (int j = 0; j < 4; ++j) acc[i][j] = vz;

    for (int kk = 0; kk < K; kk += 32) {
        __syncthreads();
#pragma unroll
        for (int i = 0; i < 2; ++i) {
            const int cb = i * 256 + w * 64;
            const int c  = cb + lane;
            const int r  = c >> 2;
            const int ko = (c & 3) << 3;
            gload_lds16(A  + (rowA0 + r) * K + kk + ko, As + cb * 8);
            gload_lds16(Bm + (rowB0 + r) * K + kk + ko, Bs + cb * 8);
        }
        __syncthreads();
        bf16x8 af[4], bfr[4];
#pragma unroll
        for (int i = 0; i < 4; ++i)
            af[i] = *(const bf16x8*)(As + (wm * 64 + i * 16 + l15) * 32 + l4 * 8);
#pragma unroll
        for (int j = 0; j < 4; ++j)
            bfr[j] = *(const bf16x8*)(Bs + (wn * 64 + j * 16 + l15) * 32 + l4 * 8);
#pragma unroll
        for (int i = 0; i < 4; ++i)
#pragma unroll
            for (int j = 0; j < 4; ++j)
                acc[i][j] = __builtin_amdgcn_mfma_f32_16x16x32_bf16(af[i], bfr[j], acc[i][j], 0, 0, 0);
    }

    const long crow0 = rowA0 + wm * 64;
    const int  ccol0 = (int)rowB0 + wn * 64;
#pragma unroll
    for (int i = 0; i < 4; ++i) {
#pragma unroll
        for (int j = 0; j < 4; ++j) {
            const int col = ccol0 + j * 16 + l15;
            const float bb = bias[col];
#pragma unroll
            for (int r = 0; r < 4; ++r) {
                const long row = crow0 + i * 16 + l4 * 4 + r;
                const float v = acc[i][j][r] + bb;
                if (OUT_BF16) ((bf16_t*)Cout)[row * N + col] = (bf16_t)v;
                else          ((float*)Cout)[row * N + col]  = v;
            }
        }
    }
}

// ---------------------------------------------------------------- V transpose repack
// Vtmp (n, h*64+d) -> Vt (b*H+h, dh, s) bf16
__global__ __launch_bounds__(256) void repack_v(const bf16_t* __restrict__ Vtmp,
                                                bf16_t* __restrict__ Vt)
{
    __shared__ bf16_t tile[64][65];
    const int t = threadIdx.x;
    const int st = blockIdx.x, bh = blockIdx.y;
    const int b = bh >> 4, h = bh & 15;
    const long nbase = (long)b * SS + st * 64;
#pragma unroll
    for (int e = 0; e < 16; ++e) {
        const int i = e * 256 + t;
        const int r = i >> 6, d = i & 63;
        tile[r][d] = Vtmp[(nbase + r) * 1024 + h * 64 + d];
    }
    __syncthreads();
#pragma unroll
    for (int e = 0; e < 16; ++e) {
        const int i = e * 256 + t;
        const int d = i >> 6, s = i & 63;
        Vt[((long)bh * DH + d) * SS + st * 64 + s] = tile[s][d];
    }
}

// ---------------------------------------------------------------- flash attention
// grid (32 q-tiles, 64 bh). 4 waves = 2x2: wave w -> (wq = w&1, wk = w>>1).
//
// R4: 32x32x16 MFMA. Per key-tile, wave (wq,wk):
//   S^T strip: keys [wk*32,+32) x q [wq*32,+32), A = K-frags from LDS (4 b128),
//   B = Q-frags PRELOADED from global into regs (0 LDS reads).
//   PV strip:  q [wq*32,+32) x d [wk*32,+32),   A = P-frags (4 b128),
//   B = V-frags (4 b128).
// 12 b128 LDS reads/wave/tile vs 18 in the 16x16 scheme (-33% on the
// LDS-BW-bound pipe). Ps is XOR-swizzled pitch-64 (octet rule: rows lane&31
// give row&7 = 0..7 per octet -> conflict-free). Ps now cross-wave => 3rd
// barrier per iter.
// Layouts (32x32x16): A[m][k]: m=lane&31, k=(lane>>5)*8+j;  B[k][n]: n=lane&31,
// k=(lane>>5)*8+j;  C/D: col=lane&31, row=(reg&3)+8*(reg>>2)+4*(lane>>5).
__global__ __launch_bounds__(256) void attn_kernel(const bf16_t* __restrict__ Qb,
                                                   const bf16_t* __restrict__ Kb,
                                                   const bf16_t* __restrict__ Vt,
                                                   bf16_t* __restrict__ Ob)
{
    __shared__ __attribute__((aligned(16))) bf16_t Ks[64 * 64];  // [key][d], swizzled
    __shared__ __attribute__((aligned(16))) bf16_t Vs[64 * 64];  // [d][key], swizzled
    __shared__ __attribute__((aligned(16))) bf16_t Ps[64 * 64];  // [q][key], swizzled
    __shared__ float lbuf[2][64];
    const int t = threadIdx.x, lane = t & 63, w = t >> 6;
    const int wq = w & 1, wk = w >> 1;
    const int l31 = lane & 31, hl = lane >> 5;
    const int qt = blockIdx.x, bh = blockIdx.y;
    const bf16_t* Qbh = Qb + (long)bh * SS * DH;
    const bf16_t* Kbh = Kb + (long)bh * SS * DH;
    const bf16_t* Vbh = Vt + (long)bh * DH * SS;

    // preload Q B-frags: frag m: Q[q = qt*64+wq*32+l31][d = 16m + 8hl + 0..7]
    const long qrowg = qt * 64 + wq * 32 + l31;
    bf16x8 qf[4];
#pragma unroll
    for (int m = 0; m < 4; ++m)
        qf[m] = *(const bf16x8*)(Qbh + qrowg * DH + 16 * m + 8 * hl);

    f32x16 oacc;
#pragma unroll
    for (int e = 0; e < 16; ++e) oacc[e] = 0.f;
    float l_sum = 0.f;

    // staging: lane handles LDS chunk L = i*256 + w*64 + lane of the 8 KB tile;
    // row = L>>3, swizzled src chunk = (L&7) ^ (row&7)
    int srow[2], scc[2];
#pragma unroll
    for (int i = 0; i < 2; ++i) {
        const int L = i * 256 + w * 64 + lane;
        srow[i] = L >> 3;
        scc[i]  = (L & 7) ^ (srow[i] & 7);
    }

    const float SC = 0.125f * 1.4426950408889634f;
    const float BI = -8.0f  * 1.4426950408889634f;

    const int rk = wk * 32 + l31;          // S^T A row (key), PV B row (d)
    const int rq = wq * 32 + l31;          // Ps row (q) for write and A-read
    const int xk = rk & 7, xq = rq & 7;

    for (int kt = 0; kt < SS / 64; ++kt) {
        __syncthreads();                   // A: prev-iter PV reads done
        const bf16_t* Ksrc = Kbh + (long)kt * 64 * DH;
#pragma unroll
        for (int i = 0; i < 2; ++i) {
            const int cb = i * 256 + w * 64;
            gload_lds16(Ksrc + srow[i] * 64 + scc[i] * 8, Ks + cb * 8);
            gload_lds16(Vbh + (long)srow[i] * SS + kt * 64 + scc[i] * 8, Vs + cb * 8);
        }
        __syncthreads();                   // B: tiles staged

        // S^T = K Q^T : D[key = rk-strip][q = wq-strip]
        f32x16 sacc;
#pragma unroll
        for (int e = 0; e < 16; ++e) sacc[e] = 0.f;
#pragma unroll
        for (int m = 0; m < 4; ++m) {
            const bf16x8 kf = *(const bf16x8*)(Ks + rk * 64 + (((2 * m + hl) ^ xk) << 3));
            sacc = __builtin_amdgcn_mfma_f32_32x32x16_bf16(kf, qf[m], sacc, 0, 0, 0);
        }

        // p = exp2(s*SC + BI); lane holds q' = l31 (col), keys = 8g + 4hl + r
#pragma unroll
        for (int g = 0; g < 4; ++g) {
            const float p0 = EXP2F(fmaf(sacc[4 * g + 0], SC, BI));
            const float p1 = EXP2F(fmaf(sacc[4 * g + 1], SC, BI));
            const float p2 = EXP2F(fmaf(sacc[4 * g + 2], SC, BI));
            const float p3 = EXP2F(fmaf(sacc[4 * g + 3], SC, BI));
            l_sum += (p0 + p1) + (p2 + p3);
            bf16x4 pk;
            pk.x = (bf16_t)p0; pk.y = (bf16_t)p1; pk.z = (bf16_t)p2; pk.w = (bf16_t)p3;
            // key chunk c = wk*4 + g (16B); half-chunk offset 4*hl
            *(bf16x4*)(Ps + rq * 64 + (((wk * 4 + g) ^ xq) << 3) + 4 * hl) = pk;
        }
        __syncthreads();                   // C: Ps visible to all waves

        // O += P V : D[q = wq-strip][d = wk-strip]
#pragma unroll
        for (int m = 0; m < 4; ++m) {
            const bf16x8 pf = *(const bf16x8*)(Ps + rq * 64 + (((2 * m + hl) ^ xq) << 3));
            const bf16x8 vf = *(const bf16x8*)(Vs + rk * 64 + (((2 * m + hl) ^ xk) << 3));
            oacc = __builtin_amdgcn_mfma_f32_32x32x16_bf16(pf, vf, oacc, 0, 0, 0);
        }
    }

    // denominator: lane's l_sum covers q' = l31 over keys (wk-strip, hl-half)
    float lt = l_sum + __shfl_xor(l_sum, 32);
    if (lane < 32) lbuf[wk][wq * 32 + lane] = lt;
    __syncthreads();

    const int b = bh >> 4, h = bh & 15;
    const long orow0 = (long)b * SS + qt * 64 + wq * 32;
    const int  ocol  = h * DH + wk * 32 + l31;
#pragma unroll
    for (int g = 0; g < 4; ++g) {
#pragma unroll
        for (int r = 0; r < 4; ++r) {
            const int qp = 8 * g + 4 * hl + r;               // q' within wq strip
            const float inv = 1.0f / (lbuf[0][wq * 32 + qp] + lbuf[1][wq * 32 + qp]);
            Ob[(orow0 + qp) * DD + ocol] = (bf16_t)(oacc[4 * g + r] * inv);
        }
    }
}

// ---------------------------------------------------------------- launch
extern "C" void kernel_launch(void* const* d_in, const int* in_sizes, int n_in,
                              void* d_out, int out_size, void* d_ws, size_t ws_size,
                              hipStream_t stream)
{
    const float* queries = (const float*)d_in[0];
    const float* Wq = (const float*)d_in[1];
    const float* bq = (const float*)d_in[2];
    const float* Wk = (const float*)d_in[3];
    const float* bk = (const float*)d_in[4];
    const float* Wv = (const float*)d_in[5];
    const float* bv = (const float*)d_in[6];
    const float* Wo = (const float*)d_in[7];
    const float* bo = (const float*)d_in[8];

    char* ws = (char*)d_ws;
    size_t off = 0;
    auto alloc = [&](size_t bytes) { size_t o = off; off += (bytes + 255) & ~(size_t)255; return o; };
    bf16_t* Xb   = (bf16_t*)(ws + alloc(8192u * 1024u * 2u));       // 16 MB
    bf16_t* Wqkv = (bf16_t*)(ws + alloc(3072u * 1024u * 2u));       // 6 MB
    bf16_t* Wob  = (bf16_t*)(ws + alloc(1024u * 1024u * 2u));       // 2 MB
    float*  bqkv = (float*) (ws + alloc(3072u * 4u));
    float2* tab  = (float2*)(ws + alloc(2048u * 512u * 8u));        // 8 MB
    bf16_t* Vtmp = (bf16_t*)(ws + alloc(8192u * 1024u * 2u));       // 16 MB
    bf16_t* Qb   = (bf16_t*)(ws + alloc(64u * 2048u * 64u * 2u));   // 16 MB
    bf16_t* Kb   = (bf16_t*)(ws + alloc(64u * 2048u * 64u * 2u));   // 16 MB
    bf16_t* Vt   = (bf16_t*)(ws + alloc(64u * 64u * 2048u * 2u));   // 16 MB
    bf16_t* Ob   = Xb;  // alias: Xb is dead after GEMM1

    cvt_kernel<<<8192, 256, 0, stream>>>(queries, Xb, 2097152);
    cvt_weights<<<4096, 256, 0, stream>>>(Wq, Wk, Wv, Wo, Wqkv, Wob);
    pack_bias<<<12, 256, 0, stream>>>(bq, bk, bv, bqkv);
    rope_tab<<<4096, 256, 0, stream>>>(tab);

    gemm_qkv_rope<<<dim3(64, 24), 256, 0, stream>>>(Xb, Wqkv, bqkv, tab, Qb, Kb, Vtmp);
    repack_v<<<dim3(32, 64), 256, 0, stream>>>(Vtmp, Vt);
    attn_kernel<<<dim3(32, 64), 256, 0, stream>>>(Qb, Kb, Vt, Ob);
    gemm_bt<0><<<dim3(64, 8), 256, 0, stream>>>(Ob, Wob, bo, d_out, 8192, 1024, 1024);
}